// Round 6
// baseline (122.948 us; speedup 1.0000x reference)
//
#include <hip/hip_runtime.h>

#define PP 16
#define DD 64
#define RR 32
#define KK 64
#define NBT 4096   // B*T

#define LOG2E 1.4426950408889634f
#define LN2   0.6931471805599453f
#define D2_CUT 25.0f   // keep pairs with d2 <= d2min + CUT; rel err ~e^-25 vs dominant term

static __device__ __forceinline__ float fast_log2(float x) { return __builtin_amdgcn_logf(x); }
static __device__ __forceinline__ float fast_exp2(float x) { return __builtin_amdgcn_exp2f(x); }
static __device__ __forceinline__ float fast_rcp(float x)  { return __builtin_amdgcn_rcpf(x); }

// One block, 1024 threads: thread t=(r,s). cc[r]=||c_r||^2; d2min over r<s; compact
// pairs with d2 <= d2min+CUT into plist as (omega, int(r*32+s)); pack c as
// c_packed[d4][r] = float4(c[r][4d4..4d4+3]) so sheaf ph1 reads are coalesced.
__global__ __launch_bounds__(1024) void prune_kernel(const float* __restrict__ c,
                                                     float* __restrict__ cc,
                                                     int* __restrict__ meta,
                                                     float2* __restrict__ plist,
                                                     float4* __restrict__ c_packed) {
    __shared__ float red[16];
    __shared__ float dmin_sh;
    __shared__ int cnt;
    const int t = threadIdx.x;
    const int r = t >> 5, s = t & 31;
    const bool active = s > r;
    const float4* c4 = (const float4*)c;

    if (t < 512) c_packed[t] = c4[(t & 31) * 16 + (t >> 5)];  // [d4][r]

    float d2 = 0.f;
#pragma unroll
    for (int d4 = 0; d4 < 16; ++d4) {
        float4 a = c4[r * 16 + d4];
        float4 b = c4[s * 16 + d4];
        float dx = a.x - b.x, dy = a.y - b.y, dz = a.z - b.z, dw = a.w - b.w;
        d2 = fmaf(dx, dx, d2); d2 = fmaf(dy, dy, d2);
        d2 = fmaf(dz, dz, d2); d2 = fmaf(dw, dw, d2);
    }
    if (t == 0) cnt = 0;
    float dm = active ? d2 : 3.4e38f;
#pragma unroll
    for (int off = 32; off > 0; off >>= 1) dm = fminf(dm, __shfl_down(dm, off, 64));
    if ((t & 63) == 0) red[t >> 6] = dm;
    __syncthreads();
    if (t < 64) {
        float v = (t < 16) ? red[t] : 3.4e38f;
#pragma unroll
        for (int off = 8; off > 0; off >>= 1) v = fminf(v, __shfl_down(v, off, 64));
        if (t == 0) dmin_sh = v;
    }
    __syncthreads();
    if (active && d2 <= dmin_sh + D2_CUT) {
        int idx = atomicAdd(&cnt, 1);
        plist[idx] = make_float2(fast_exp2(-d2 * LOG2E), __int_as_float(t));
    }
    if (t < RR) {
        float a2 = 0.f;
#pragma unroll
        for (int d4 = 0; d4 < 16; ++d4) {
            float4 v = c4[t * 16 + d4];
            a2 = fmaf(v.x, v.x, a2); a2 = fmaf(v.y, v.y, a2);
            a2 = fmaf(v.z, v.z, a2); a2 = fmaf(v.w, v.w, a2);
        }
        cc[t] = a2;
    }
    __syncthreads();
    if (t == 0) meta[0] = cnt;
}

__global__ __launch_bounds__(256, 4) void sheaf3_kernel(
    const float* __restrict__ m, const float* __restrict__ w,
    const float* __restrict__ p, const float* __restrict__ cc,
    const int* __restrict__ meta, const float2* __restrict__ plist,
    const float4* __restrict__ c_packed, float* __restrict__ partials) {
    __shared__ float sm_mass[PP * 36];   // start_mass [p][r], pad 36
    __shared__ float sm_tot[RR];         // column totals (ds_add_f32)
    __shared__ float sm_pbT[KK * 33];    // pbar^T [k][r], stride 33
    __shared__ float sm_plT[KK * 33];    // (pbar*log2 pbar)^T [k][r]
    __shared__ float sred[4];

    const int tid  = threadIdx.x;
    const int bt   = blockIdx.x;
    const int lane = tid & 63;
    const int wv   = tid >> 6;
    const int np   = meta[0];   // uniform -> scalar load

    if (tid < RR) sm_tot[tid] = 0.f;
    __syncthreads();

    // ---- phase 1: logits[p][r] = 2*m.c - cc[r]  (||m||^2 cancels in softmax).
    //      m, c read from GLOBAL (VMEM pipe); softmax in-register; mass -> LDS;
    //      column totals via LDS float atomics. ----
    {
        const int r  = tid & 31;
        const int pg = tid >> 5;  // rows pg, pg+8
        const float4* m4a = (const float4*)(m + (size_t)bt * PP * DD) + pg * 16;
        const float4* m4b = m4a + 8 * 16;
        float acc0 = 0.f, acc1 = 0.f;
#pragma unroll
        for (int d4 = 0; d4 < 16; ++d4) {
            float4 cv = c_packed[d4 * 32 + r];   // coalesced, L1/L2-hot
            float4 ma = m4a[d4];                  // 2-address broadcast, L1-hot
            float4 mb = m4b[d4];
            acc0 = fmaf(ma.x, cv.x, acc0); acc0 = fmaf(ma.y, cv.y, acc0);
            acc0 = fmaf(ma.z, cv.z, acc0); acc0 = fmaf(ma.w, cv.w, acc0);
            acc1 = fmaf(mb.x, cv.x, acc1); acc1 = fmaf(mb.y, cv.y, acc1);
            acc1 = fmaf(mb.z, cv.z, acc1); acc1 = fmaf(mb.w, cv.w, acc1);
        }
        float ccr = cc[r];
        float l0 = fmaf(2.f, acc0, -ccr);
        float l1 = fmaf(2.f, acc1, -ccr);
        float mx0 = l0, mx1 = l1;
#pragma unroll
        for (int off = 1; off <= 16; off <<= 1) {
            mx0 = fmaxf(mx0, __shfl_xor(mx0, off, 64));
            mx1 = fmaxf(mx1, __shfl_xor(mx1, off, 64));
        }
        float e0 = fast_exp2((l0 - mx0) * LOG2E);
        float e1 = fast_exp2((l1 - mx1) * LOG2E);
        float s0 = e0, s1 = e1;
#pragma unroll
        for (int off = 1; off <= 16; off <<= 1) {
            s0 += __shfl_xor(s0, off, 64);
            s1 += __shfl_xor(s1, off, 64);
        }
        float w0 = w[(size_t)bt * PP + pg];
        float w1 = w[(size_t)bt * PP + pg + 8];
        float v0 = e0 * (w0 * fast_rcp(s0));
        float v1 = e1 * (w1 * fast_rcp(s1));
        sm_mass[pg * 36 + r]       = v0;
        sm_mass[(pg + 8) * 36 + r] = v1;
        float tp = v0 + v1;
        tp += __shfl_xor(tp, 32, 64);            // combine the wave's two pg halves
        if (lane < 32) atomicAdd(&sm_tot[r], tp);  // ds_add_f32, bank r
    }
    __syncthreads();

    // ---- phase 4: pbar[r][k] = inv_r * sum_p p[p][k]*mass[p][r].
    //      thread = (r-pair, k-quad): mass spread b64, p coalesced global. ----
    {
        const int rp = lane & 15;            // r0 = 2*rp
        const int kb = lane >> 4;            // 0..3
        const int r0 = rp * 2;
        const int k0 = wv * 16 + kb * 4;
        const float4* p4 = (const float4*)(p + (size_t)bt * PP * KK);
        float2 t2 = *(const float2*)&sm_tot[r0];
        float inv0 = fast_rcp(t2.x + 1e-6f);
        float inv1 = fast_rcp(t2.y + 1e-6f);
        float a0[4] = {0.f, 0.f, 0.f, 0.f};
        float a1[4] = {0.f, 0.f, 0.f, 0.f};
#pragma unroll
        for (int pi = 0; pi < PP; ++pi) {
            float2 mv = *(const float2*)&sm_mass[pi * 36 + r0];   // spread b64
            float4 pv = p4[pi * 16 + (k0 >> 2)];                   // coalesced
            a0[0] = fmaf(mv.x, pv.x, a0[0]); a0[1] = fmaf(mv.x, pv.y, a0[1]);
            a0[2] = fmaf(mv.x, pv.z, a0[2]); a0[3] = fmaf(mv.x, pv.w, a0[3]);
            a1[0] = fmaf(mv.y, pv.x, a1[0]); a1[1] = fmaf(mv.y, pv.y, a1[1]);
            a1[2] = fmaf(mv.y, pv.z, a1[2]); a1[3] = fmaf(mv.y, pv.w, a1[3]);
        }
#pragma unroll
        for (int kk = 0; kk < 4; ++kk) {
            int ko = (k0 + kk) * 33;
            float pb0 = a0[kk] * inv0;
            float pb1 = a1[kk] * inv1;
            float lg0 = fast_log2(pb0 + 1e-8f);
            float lg1 = fast_log2(pb1 + 1e-8f);
            sm_pbT[ko + r0]     = pb0;
            sm_pbT[ko + r0 + 1] = pb1;
            sm_plT[ko + r0]     = pb0 * lg0;
            sm_plT[ko + r0 + 1] = pb1 * lg1;
        }
    }
    __syncthreads();

    // ---- phase 5: pruned pairs: omega * [pr*l2pr + ps*l2ps - (pr+ps)*l2(mid)] ----
    {
        const int k = lane;
        float acc = 0.f;
        for (int i = wv; i < np; i += 4) {
            float2 e = plist[i];                 // wave-uniform, L2-hot
            int rs = __float_as_int(e.y);
            int rr = rs >> 5, ss = rs & 31;
            float par = sm_pbT[k * 33 + rr];
            float pas = sm_pbT[k * 33 + ss];
            float lar = sm_plT[k * 33 + rr];
            float las = sm_plT[k * 33 + ss];
            float sum = par + pas;
            float t   = lar + las;
            float lm  = fast_log2(fmaf(0.5f, sum, 1e-8f));
            t = fmaf(-sum, lm, t);
            acc = fmaf(e.x, t, acc);
        }
#pragma unroll
        for (int off = 32; off > 0; off >>= 1) acc += __shfl_down(acc, off, 64);
        if (k == 0) sred[wv] = acc;
    }
    __syncthreads();
    if (tid == 0) {
        float tot = (sred[0] + sred[1]) + (sred[2] + sred[3]);
        partials[bt] = tot * (0.5f * LN2 / 496.0f);
    }
}

__global__ __launch_bounds__(256) void reduce_kernel(const float* __restrict__ partials,
                                                     float* __restrict__ out) {
    __shared__ float sred[4];
    const int tid = threadIdx.x;
    const float4* p4 = (const float4*)partials;  // 1024 float4
    float acc = 0.f;
#pragma unroll
    for (int i = 0; i < 4; ++i) {
        float4 v = p4[tid + 256 * i];
        acc += (v.x + v.y) + (v.z + v.w);
    }
#pragma unroll
    for (int off = 32; off > 0; off >>= 1) acc += __shfl_down(acc, off, 64);
    if ((tid & 63) == 0) sred[tid >> 6] = acc;
    __syncthreads();
    if (tid == 0) out[0] = (sred[0] + sred[1]) + (sred[2] + sred[3]);
}

extern "C" void kernel_launch(void* const* d_in, const int* in_sizes, int n_in,
                              void* d_out, int out_size, void* d_ws, size_t ws_size,
                              hipStream_t stream) {
    const float* m = (const float*)d_in[0];
    const float* w = (const float*)d_in[1];
    const float* p = (const float*)d_in[2];
    const float* c = (const float*)d_in[3];
    float* out = (float*)d_out;

    float* wsf       = (float*)d_ws;
    int*    meta     = (int*)d_ws;             // [0]=np
    float*  cc       = wsf + 64;               // 32 floats
    float2* plist    = (float2*)(wsf + 128);   // up to 496 float2
    float4* c_packed = (float4*)(wsf + 2048);  // 512 float4 (8 KB), [d4][r]
    float*  partials = wsf + 4096;             // 4096 floats

    prune_kernel<<<1, 1024, 0, stream>>>(c, cc, meta, plist, c_packed);
    sheaf3_kernel<<<NBT, 256, 0, stream>>>(m, w, p, cc, meta, plist, c_packed, partials);
    reduce_kernel<<<1, 256, 0, stream>>>(partials, out);
}